// Round 3
// baseline (567.706 us; speedup 1.0000x reference)
//
#include <hip/hip_runtime.h>
#include <math.h>

// Problem constants
#define BB 4
#define CC 64
#define HH 128
#define WW 128
#define GG 8
#define COO 64
#define HWC (HH*WW)

typedef float f32x16 __attribute__((ext_vector_type(16)));
typedef __bf16 bf16x8 __attribute__((ext_vector_type(8)));

__device__ __forceinline__ unsigned short bf16_rn(float f) {
    unsigned int u = __float_as_uint(f);
    unsigned int r = (u + 0x7fffu + ((u >> 16) & 1u)) >> 16;
    return (unsigned short)r;
}
__device__ __forceinline__ float b2f(unsigned short u) {
    return __uint_as_float(((unsigned int)u) << 16);
}

// ---------------------------------------------------------------------------
// NCHW fp32 -> NHWC bf16 (C=64), LDS-tiled for coalescing both sides.
// ---------------------------------------------------------------------------
__global__ __launch_bounds__(256) void to_nhwc_kernel(const float* __restrict__ in,
                                                      unsigned short* __restrict__ out) {
    __shared__ unsigned short lds[64][66];
    const int b = blockIdx.y;
    const int pix0 = blockIdx.x * 64;
    const int t = threadIdx.x;
    {
        const int p = t & 63, q = t >> 6;
#pragma unroll
        for (int i = 0; i < 16; i++) {
            int c = i * 4 + q;
            lds[c][p] = bf16_rn(in[((size_t)b * 64 + c) * HWC + pix0 + p]);
        }
    }
    __syncthreads();
    {
        const int c = t & 63, pb = t >> 6;
#pragma unroll
        for (int i = 0; i < 16; i++) {
            int pl = i * 4 + pb;
            out[((size_t)b * HWC + pix0 + pl) * 64 + c] = lds[c][pl];
        }
    }
}

// ---------------------------------------------------------------------------
// Interleave x & share (NCHW fp32) into NCHW uint32: lo16 = bf16(x),
// hi16 = bf16(share). One 4B gather in the deform kernel then serves BOTH
// deform convs for one (channel, corner).
// ---------------------------------------------------------------------------
__global__ __launch_bounds__(256) void pack_xs_kernel(const float* __restrict__ x,
                                                      const float* __restrict__ s,
                                                      unsigned int* __restrict__ xs, int n) {
    int i = blockIdx.x * 256 + threadIdx.x;
    if (i < n) {
        xs[i] = (unsigned int)bf16_rn(x[i]) | ((unsigned int)bf16_rn(s[i]) << 16);
    }
}

// ---------------------------------------------------------------------------
// Pack conv weights [Cout][CinTot][3][3] fp32 into MFMA A-fragment order:
// wp[((seg*9+kk)*4+cg)][co_pad][16c] bf16, zero-padded for co >= Cout.
// ---------------------------------------------------------------------------
__global__ void pack_w_kernel(const float* __restrict__ w, unsigned short* __restrict__ wp,
                              int Cout, int COP, int CinTot, int n) {
    int idx = blockIdx.x * 256 + threadIdx.x;
    if (idx >= n) return;
    int i  = idx & 15;
    int co = (idx >> 4) % COP;
    int t  = idx / (16 * COP);       // t = (seg*9+kk)*4+cg
    int cg = t & 3;
    int kk = (t >> 2) % 9;
    int seg = t / 36;
    int cin = seg * 64 + cg * 16 + i;
    float v = (co < Cout) ? w[((size_t)co * CinTot + cin) * 9 + kk] : 0.f;
    wp[idx] = bf16_rn(v);
}

// ---------------------------------------------------------------------------
// Implicit-GEMM 3x3 conv via mfma_f32_32x32x16_bf16.
// Wave tile: 32 Cout x 128 pix (one image row). Block = 4 waves = 4 rows.
// grid = (B*H/4, COP/32). Inputs are NHWC bf16 segments of 64 channels.
// out_mode: 0 = NCHW fp32, 1 = NHWC bf16, 2 = NCHW bf16
// act: 0 none, 1 leaky(0.1), 2 sigmoid, 3 sigmoid for co>=144
// ---------------------------------------------------------------------------
template<int NSEG>
__global__ __launch_bounds__(256, 4) void conv_mfma_kernel(
    const unsigned short* __restrict__ in0,
    const unsigned short* __restrict__ in1,
    const unsigned short* __restrict__ wp,
    const float* __restrict__ bias,
    void* __restrict__ out,
    int Cout, int COP, int out_mode, int act)
{
    const int lane = threadIdx.x & 63;
    const int wid  = threadIdx.x >> 6;
    const int l31  = lane & 31;
    const int half = lane >> 5;
    const int b    = blockIdx.x >> 5;
    const int r    = ((blockIdx.x & 31) << 2) + wid;   // image row, wave-uniform
    const int co0  = blockIdx.y * 32;

    f32x16 acc[4];
#pragma unroll
    for (int nt = 0; nt < 4; nt++)
#pragma unroll
        for (int rg = 0; rg < 16; rg++) acc[nt][rg] = 0.f;

    bf16x8 bz;
#pragma unroll
    for (int i = 0; i < 8; i++) bz[i] = (__bf16)0.f;

#pragma unroll
    for (int seg = 0; seg < NSEG; seg++) {
        const unsigned short* in = seg ? in1 : in0;
        const unsigned short* inb = in + (size_t)b * HWC * 64;
        for (int kk = 0; kk < 9; kk++) {
            const int rr = r + kk / 3 - 1;
            if ((unsigned)rr < (unsigned)HH) {
                const int dxo = kk % 3 - 1;
                const size_t rowbase = (size_t)rr * WW * 64;
#pragma unroll
                for (int cg = 0; cg < 4; cg++) {
                    bf16x8 afrag = *(const bf16x8*)(wp +
                        ((size_t)(((seg * 9 + kk) * 4 + cg) * COP + co0 + l31) * 16 + half * 8));
#pragma unroll
                    for (int nt = 0; nt < 4; nt++) {
                        const int cc = nt * 32 + l31 + dxo;
                        bf16x8 bfrag = bz;
                        if ((unsigned)cc < (unsigned)WW)
                            bfrag = *(const bf16x8*)(inb + rowbase + (size_t)cc * 64 + cg * 16 + half * 8);
                        acc[nt] = __builtin_amdgcn_mfma_f32_32x32x16_bf16(afrag, bfrag, acc[nt], 0, 0, 0);
                    }
                }
            }
        }
    }

    // Epilogue
#pragma unroll
    for (int nt = 0; nt < 4; nt++) {
#pragma unroll
        for (int rg = 0; rg < 16; rg++) {
            const int row = (rg & 3) + 8 * (rg >> 2) + 4 * half;
            const int co = co0 + row;
            if (co < Cout) {
                float v = acc[nt][rg] + bias[co];
                if (act == 1)      v = (v >= 0.f) ? v : 0.1f * v;
                else if (act == 2) v = 1.f / (1.f + __expf(-v));
                else if (act == 3 && co >= 144) v = 1.f / (1.f + __expf(-v));
                const int pix = r * WW + nt * 32 + l31;
                if (out_mode == 0)
                    ((float*)out)[((size_t)b * Cout + co) * HWC + pix] = v;
                else if (out_mode == 1)
                    ((unsigned short*)out)[((size_t)b * HWC + pix) * Cout + co] = bf16_rn(v);
                else
                    ((unsigned short*)out)[((size_t)b * Cout + co) * HWC + pix] = bf16_rn(v);
            }
        }
    }
}

// ---------------------------------------------------------------------------
// Fused dual modulated deformable conv, gather-optimized.
// xs: NCHW interleaved uint32 {lo=bf16(x), hi=bf16(share)} -> each 4B dword
// gather serves both tensors for one (channel, corner). Consecutive lanes
// (consecutive w) have near-consecutive corner indices -> ~5 cache lines per
// wave-gather instead of 64 (NHWC layout). om NCHW bf16, em NCHW bf16.
// One thread per (b,g,h,w); om/em values hoisted out of the kk loop.
// ---------------------------------------------------------------------------
__global__ __launch_bounds__(256, 4) void deform_fused_kernel(
    const unsigned int* __restrict__ xs,
    const unsigned short* __restrict__ om, const unsigned short* __restrict__ em,
    const float* __restrict__ wdc, const float* __restrict__ bdc,
    float* __restrict__ outx, float* __restrict__ outs)
{
    const int tid = blockIdx.x * 256 + threadIdx.x;
    const int w = tid & (WW - 1);
    const int h = (tid >> 7) & (HH - 1);
    const int g = (tid >> 14) & (GG - 1);
    const int b = tid >> 17;

    const int pix = h * WW + w;
    const unsigned short* omb = om + (size_t)b * 216 * HWC + pix;
    const unsigned short* emb = em + (size_t)b * 72 * HWC + pix;
    const unsigned int* xsb = xs + ((size_t)b * 64 + g * 8) * HWC;

    // Hoist all offset/mask loads (removes per-kk dependent-load stalls)
    float dys[9], dxs[9], m1s[9], m2s[9];
#pragma unroll
    for (int kk = 0; kk < 9; kk++) {
        dys[kk] = b2f(omb[(size_t)(g * 18 + kk * 2) * HWC]);
        dxs[kk] = b2f(omb[(size_t)(g * 18 + kk * 2 + 1) * HWC]);
        m1s[kk] = b2f(omb[(size_t)(144 + g * 9 + kk) * HWC]);
        m2s[kk] = b2f(emb[(size_t)(g * 9 + kk) * HWC]);
    }

    float accx[8], accs[8];
#pragma unroll
    for (int o = 0; o < 8; o++) { accx[o] = 0.f; accs[o] = 0.f; }

    for (int kk = 0; kk < 9; kk++) {
        const float py = (float)(h - 1 + kk / 3) + dys[kk];
        const float px = (float)(w - 1 + kk % 3) + dxs[kk];
        const float y0f = floorf(py), x0f = floorf(px);
        const float ly = py - y0f, lx = px - x0f;
        const int y0 = (int)y0f, x0 = (int)x0f;
        const int y1 = y0 + 1, x1 = x0 + 1;
        const bool vy0 = (y0 >= 0) && (y0 < HH), vy1 = (y1 >= 0) && (y1 < HH);
        const bool vx0 = (x0 >= 0) && (x0 < WW), vx1 = (x1 >= 0) && (x1 < WW);
        float w00 = (1.f - ly) * (1.f - lx); if (!(vy0 && vx0)) w00 = 0.f;
        float w01 = (1.f - ly) * lx;         if (!(vy0 && vx1)) w01 = 0.f;
        float w10 = ly * (1.f - lx);         if (!(vy1 && vx0)) w10 = 0.f;
        float w11 = ly * lx;                 if (!(vy1 && vx1)) w11 = 0.f;
        const int cy0 = min(max(y0, 0), HH - 1), cy1 = min(max(y1, 0), HH - 1);
        const int cx0 = min(max(x0, 0), WW - 1), cx1 = min(max(x1, 0), WW - 1);
        const int i00 = cy0 * WW + cx0, i01 = cy0 * WW + cx1;
        const int i10 = cy1 * WW + cx0, i11 = cy1 * WW + cx1;
        const float m1 = m1s[kk], m2 = m2s[kk];

        // Issue all 32 gathers for this kk (independent dword loads)
        unsigned int u00[8], u01[8], u10[8], u11[8];
#pragma unroll
        for (int c = 0; c < 8; c++) {
            const unsigned int* xc = xsb + (size_t)c * HWC;
            u00[c] = xc[i00]; u01[c] = xc[i01];
            u10[c] = xc[i10]; u11[c] = xc[i11];
        }

#pragma unroll
        for (int c = 0; c < 8; c++) {
            float x00 = __uint_as_float(u00[c] << 16), s00 = __uint_as_float(u00[c] & 0xffff0000u);
            float x01 = __uint_as_float(u01[c] << 16), s01 = __uint_as_float(u01[c] & 0xffff0000u);
            float x10 = __uint_as_float(u10[c] << 16), s10 = __uint_as_float(u10[c] & 0xffff0000u);
            float x11 = __uint_as_float(u11[c] << 16), s11 = __uint_as_float(u11[c] & 0xffff0000u);
            float vx = w00 * x00 + w01 * x01 + w10 * x10 + w11 * x11;
            float vs = w00 * s00 + w01 * s01 + w10 * s10 + w11 * s11;
            vx *= m1;
            vs *= m2;
#pragma unroll
            for (int o = 0; o < 8; o++) {
                const float wv = wdc[((size_t)((g * 8 + o) * 8 + c)) * 9 + kk];
                accx[o] = fmaf(vx, wv, accx[o]);
                accs[o] = fmaf(vs, wv, accs[o]);
            }
        }
    }

#pragma unroll
    for (int o = 0; o < 8; o++) {
        const float bv = bdc[g * 8 + o];
        outx[((size_t)(b * COO + g * 8 + o)) * HWC + pix] = accx[o] + bv;
        outs[((size_t)(b * COO + g * 8 + o)) * HWC + pix] = accs[o] + bv;
    }
}

// ---------------------------------------------------------------------------
extern "C" void kernel_launch(void* const* d_in, const int* in_sizes, int n_in,
                              void* d_out, int out_size, void* d_ws, size_t ws_size,
                              hipStream_t stream) {
    const float* x      = (const float*)d_in[0];
    const float* share  = (const float*)d_in[1];
    const float* offf   = (const float*)d_in[2];
    const float* w_om   = (const float*)d_in[3];
    const float* b_om   = (const float*)d_in[4];
    const float* w_em1  = (const float*)d_in[5];
    const float* b_em1  = (const float*)d_in[6];
    const float* w_em2  = (const float*)d_in[7];
    const float* b_em2  = (const float*)d_in[8];
    const float* w_dc   = (const float*)d_in[9];
    const float* b_dc   = (const float*)d_in[10];

    // Workspace layout
    unsigned int* xs = (unsigned int*)d_ws;           // 4194304 u32 (16.8MB)
    unsigned short* us = (unsigned short*)(xs + 4194304);
    unsigned short* shh    = us;                      // 4194304 ush (share NHWC)
    unsigned short* ofh    = shh + 4194304;           // 4194304 (offf NHWC)
    unsigned short* emh    = ofh + 4194304;           // 4194304 (em_mid NHWC)
    unsigned short* om_b   = emh + 4194304;           // 14155776 (om NCHW bf16)
    unsigned short* em_b   = om_b + 14155776;         // 4718592 (em NCHW bf16)
    unsigned short* wp_om  = em_b + 4718592;          // 129024
    unsigned short* wp_em1 = wp_om + 129024;          // 73728
    unsigned short* wp_em2 = wp_em1 + 73728;          // 55296

    float* outx = (float*)d_out;
    float* outs = outx + 4194304;

    dim3 blk(256);

    // Repack inputs
    pack_xs_kernel<<<(4194304 + 255) / 256, blk, 0, stream>>>(x, share, xs, 4194304);
    to_nhwc_kernel<<<dim3(HWC / 64, BB), blk, 0, stream>>>(share, shh);
    to_nhwc_kernel<<<dim3(HWC / 64, BB), blk, 0, stream>>>(offf, ofh);

    // Pack weights
    pack_w_kernel<<<(129024 + 255) / 256, blk, 0, stream>>>(w_om,  wp_om,  216, 224, 64,  129024);
    pack_w_kernel<<<(73728  + 255) / 256, blk, 0, stream>>>(w_em1, wp_em1, 64,  64,  128, 73728);
    pack_w_kernel<<<(55296  + 255) / 256, blk, 0, stream>>>(w_em2, wp_em2, 72,  96,  64,  55296);

    // om = conv(offset_feat) 64->216, sigmoid on mask channels, NCHW bf16
    conv_mfma_kernel<1><<<dim3(BB * HH / 4, 7), blk, 0, stream>>>(
        ofh, nullptr, wp_om, b_om, om_b, 216, 224, 2, 3);
    // em_mid = leaky(conv(concat(share, offf))) 128->64, NHWC bf16
    conv_mfma_kernel<2><<<dim3(BB * HH / 4, 2), blk, 0, stream>>>(
        shh, ofh, wp_em1, b_em1, emh, 64, 64, 1, 1);
    // em = sigmoid(conv(em_mid)) 64->72, NCHW bf16
    conv_mfma_kernel<1><<<dim3(BB * HH / 4, 3), blk, 0, stream>>>(
        emh, nullptr, wp_em2, b_em2, em_b, 72, 96, 2, 2);

    // fused dual deformable conv
    deform_fused_kernel<<<dim3(BB * GG * HH * WW / 256), blk, 0, stream>>>(
        xs, om_b, em_b, w_dc, b_dc, outx, outs);
}